// Round 1
// baseline (4047.865 us; speedup 1.0000x reference)
//
#include <hip/hip_runtime.h>
#include <math.h>

#define NTOK 20000
#define EMB 512
#define HID 1024
#define VD 2048
#define ML 20
#define NBATCH 128
#define KREG 36
#define NSTEP 19
#define XIN_D 2560
#define G3 3072

// int workspace layout (indices into (int*)d_ws)
#define WI_ORDER 0
#define WI_DEC 128
#define WI_BATCH 256
#define WI_OFF 288
#define WI_P 320

static __device__ __forceinline__ float sigmoidf_(float x) { return 1.f / (1.f + expf(-x)); }

// ---------------------------------------------------------------- prep
__global__ __launch_bounds__(128) void prep_kernel(const int* __restrict__ cap_len,
                                                   int* __restrict__ wsI) {
    __shared__ int cl[NBATCH], sord[NBATCH], sdec[NBATCH], sbat[NSTEP];
    int b = threadIdx.x;
    cl[b] = cap_len[b];
    __syncthreads();
    int my = cl[b], rank = 0;
    for (int j = 0; j < NBATCH; ++j) {
        int o = cl[j];
        rank += (o > my) || (o == my && j < b);
    }
    sord[rank] = b;
    sdec[rank] = my - 1;
    __syncthreads();
    wsI[WI_ORDER + b] = sord[b];
    wsI[WI_DEC + b] = sdec[b];
    if (b < NSTEP) {
        int c = 0;
        for (int s = 0; s < NBATCH; ++s) c += (sdec[s] > b);
        sbat[b] = c;
        wsI[WI_BATCH + b] = c;
    }
    __syncthreads();
    if (b == 0) {
        int run = 0;
        for (int t = 0; t < NSTEP; ++t) { wsI[WI_OFF + t] = run; run += sbat[t]; }
        wsI[WI_P] = run;
    }
}

// ---------------------------------------------------------------- h = 0
__global__ __launch_bounds__(256) void h_init_kernel(float* __restrict__ h) {
    h[blockIdx.x * 256 + threadIdx.x] = 0.f;
}

// ---------------------------------------------------------------- pv GEMM (NN, A-indirect)
// pvw[(s*36+k)][j] = relu( v[order[s],k,:] @ Wv[:,j] + bv[j] ) * wa[j]
__global__ __launch_bounds__(256) void pv_gemm_kernel(const float* __restrict__ v,
                                                      const float* __restrict__ Wv,
                                                      const float* __restrict__ bv,
                                                      const float* __restrict__ wa,
                                                      const int* __restrict__ wsI,
                                                      float* __restrict__ pvw) {
    __shared__ __align__(16) float As[16][68];
    __shared__ __align__(16) float Bs[16][64];
    const int m0 = blockIdx.y * 64;
    const int j0 = blockIdx.x * 64;
    const int tid = threadIdx.x;
    const int tx = tid & 15, ty = tid >> 4;
    const int mr = tid >> 2, kq = tid & 3;
    const int gm = m0 + mr;
    const int s = gm / KREG, kk_ = gm % KREG;
    const float* aRow = v + ((size_t)wsI[WI_ORDER + s] * KREG + kk_) * VD + kq * 4;

    float acc[4][4] = {};
    for (int kc = 0; kc < VD; kc += 16) {
        float4 a4 = *(const float4*)(aRow + kc);
        As[kq * 4 + 0][mr] = a4.x; As[kq * 4 + 1][mr] = a4.y;
        As[kq * 4 + 2][mr] = a4.z; As[kq * 4 + 3][mr] = a4.w;
        float4 b4 = *(const float4*)(Wv + (size_t)(kc + (tid >> 4)) * HID + j0 + (tid & 15) * 4);
        *(float4*)&Bs[tid >> 4][(tid & 15) * 4] = b4;
        __syncthreads();
#pragma unroll
        for (int kk = 0; kk < 16; ++kk) {
            float4 a = *(const float4*)&As[kk][ty * 4];
            float4 w = *(const float4*)&Bs[kk][tx * 4];
            acc[0][0] += a.x * w.x; acc[0][1] += a.x * w.y; acc[0][2] += a.x * w.z; acc[0][3] += a.x * w.w;
            acc[1][0] += a.y * w.x; acc[1][1] += a.y * w.y; acc[1][2] += a.y * w.z; acc[1][3] += a.y * w.w;
            acc[2][0] += a.z * w.x; acc[2][1] += a.z * w.y; acc[2][2] += a.z * w.z; acc[2][3] += a.z * w.w;
            acc[3][0] += a.w * w.x; acc[3][1] += a.w * w.y; acc[3][2] += a.w * w.z; acc[3][3] += a.w * w.w;
        }
        __syncthreads();
    }
    const int col = j0 + tx * 4;
    float4 bvv = *(const float4*)(bv + col);
    float4 wav = *(const float4*)(wa + col);
#pragma unroll
    for (int i = 0; i < 4; ++i) {
        int row = m0 + ty * 4 + i;
        float4 o;
        o.x = fmaxf(acc[i][0] + bvv.x, 0.f) * wav.x;
        o.y = fmaxf(acc[i][1] + bvv.y, 0.f) * wav.y;
        o.z = fmaxf(acc[i][2] + bvv.z, 0.f) * wav.z;
        o.w = fmaxf(acc[i][3] + bvv.w, 0.f) * wav.w;
        *(float4*)&pvw[(size_t)row * HID + col] = o;
    }
}

// ---------------------------------------------------------------- pq GEMM (NN, split-K=8) -> partial
__global__ __launch_bounds__(256) void pq_gemm_kernel(const float* __restrict__ h,
                                                      const float* __restrict__ Wq,
                                                      const int* __restrict__ wsI, int t,
                                                      float* __restrict__ part) {
    const int nb = wsI[WI_BATCH + t];
    const int m0 = blockIdx.y * 64;
    if (m0 >= nb) return;
    const int j0 = blockIdx.x * 64;
    const int sl = blockIdx.z;
    const int kbase = sl * 128;
    __shared__ __align__(16) float As[16][68];
    __shared__ __align__(16) float Bs[16][64];
    const int tid = threadIdx.x;
    const int tx = tid & 15, ty = tid >> 4;
    const int mr = tid >> 2, kq = tid & 3;
    const float* aRow = h + (size_t)(m0 + mr) * HID + kq * 4;

    float acc[4][4] = {};
    for (int kc = kbase; kc < kbase + 128; kc += 16) {
        float4 a4 = *(const float4*)(aRow + kc);
        As[kq * 4 + 0][mr] = a4.x; As[kq * 4 + 1][mr] = a4.y;
        As[kq * 4 + 2][mr] = a4.z; As[kq * 4 + 3][mr] = a4.w;
        float4 b4 = *(const float4*)(Wq + (size_t)(kc + (tid >> 4)) * HID + j0 + (tid & 15) * 4);
        *(float4*)&Bs[tid >> 4][(tid & 15) * 4] = b4;
        __syncthreads();
#pragma unroll
        for (int kk = 0; kk < 16; ++kk) {
            float4 a = *(const float4*)&As[kk][ty * 4];
            float4 w = *(const float4*)&Bs[kk][tx * 4];
            acc[0][0] += a.x * w.x; acc[0][1] += a.x * w.y; acc[0][2] += a.x * w.z; acc[0][3] += a.x * w.w;
            acc[1][0] += a.y * w.x; acc[1][1] += a.y * w.y; acc[1][2] += a.y * w.z; acc[1][3] += a.y * w.w;
            acc[2][0] += a.z * w.x; acc[2][1] += a.z * w.y; acc[2][2] += a.z * w.z; acc[2][3] += a.z * w.w;
            acc[3][0] += a.w * w.x; acc[3][1] += a.w * w.y; acc[3][2] += a.w * w.z; acc[3][3] += a.w * w.w;
        }
        __syncthreads();
    }
#pragma unroll
    for (int i = 0; i < 4; ++i) {
        int row = m0 + ty * 4 + i;
        float4 o; o.x = acc[i][0]; o.y = acc[i][1]; o.z = acc[i][2]; o.w = acc[i][3];
        *(float4*)&part[((size_t)sl * NBATCH + row) * HID + j0 + tx * 4] = o;
    }
}

// ---------------------------------------------------------------- generic NT split-K GEMM (gi, gh)
// part[sl][m][j] = sum_{k in slice} A[m][k] * W[j][k]   (lda == ldw == Ktot)
__global__ __launch_bounds__(256) void gemm_nt_splitk_kernel(const float* __restrict__ A, int lda,
                                                             const float* __restrict__ W,
                                                             const int* __restrict__ wsI, int t,
                                                             int N, int Kper,
                                                             float* __restrict__ part) {
    const int nb = wsI[WI_BATCH + t];
    const int m0 = blockIdx.y * 64;
    if (m0 >= nb) return;
    const int j0 = blockIdx.x * 64;
    const int sl = blockIdx.z;
    const int kbase = sl * Kper;
    __shared__ __align__(16) float As[16][68];
    __shared__ __align__(16) float Ws[16][68];
    const int tid = threadIdx.x;
    const int tx = tid & 15, ty = tid >> 4;
    const int mr = tid >> 2, kq = tid & 3;
    const float* aRow = A + (size_t)(m0 + mr) * lda + kq * 4;
    const float* wRow = W + (size_t)(j0 + mr) * lda + kq * 4;

    float acc[4][4] = {};
    for (int kc = kbase; kc < kbase + Kper; kc += 16) {
        float4 a4 = *(const float4*)(aRow + kc);
        float4 w4 = *(const float4*)(wRow + kc);
        As[kq * 4 + 0][mr] = a4.x; As[kq * 4 + 1][mr] = a4.y;
        As[kq * 4 + 2][mr] = a4.z; As[kq * 4 + 3][mr] = a4.w;
        Ws[kq * 4 + 0][mr] = w4.x; Ws[kq * 4 + 1][mr] = w4.y;
        Ws[kq * 4 + 2][mr] = w4.z; Ws[kq * 4 + 3][mr] = w4.w;
        __syncthreads();
#pragma unroll
        for (int kk = 0; kk < 16; ++kk) {
            float4 a = *(const float4*)&As[kk][ty * 4];
            float4 w = *(const float4*)&Ws[kk][tx * 4];
            acc[0][0] += a.x * w.x; acc[0][1] += a.x * w.y; acc[0][2] += a.x * w.z; acc[0][3] += a.x * w.w;
            acc[1][0] += a.y * w.x; acc[1][1] += a.y * w.y; acc[1][2] += a.y * w.z; acc[1][3] += a.y * w.w;
            acc[2][0] += a.z * w.x; acc[2][1] += a.z * w.y; acc[2][2] += a.z * w.z; acc[2][3] += a.z * w.w;
            acc[3][0] += a.w * w.x; acc[3][1] += a.w * w.y; acc[3][2] += a.w * w.z; acc[3][3] += a.w * w.w;
        }
        __syncthreads();
    }
#pragma unroll
    for (int i = 0; i < 4; ++i) {
        int row = m0 + ty * 4 + i;
        float4 o; o.x = acc[i][0]; o.y = acc[i][1]; o.z = acc[i][2]; o.w = acc[i][3];
        *(float4*)&part[((size_t)sl * NBATCH + row) * N + j0 + tx * 4] = o;
    }
}

// ---------------------------------------------------------------- logits GEMM (NT) -> packed d_out
__global__ __launch_bounds__(256) void logits_kernel(const float* __restrict__ h,
                                                     const float* __restrict__ Wfc,
                                                     const float* __restrict__ bfc,
                                                     const int* __restrict__ wsI, int t,
                                                     float* __restrict__ out) {
    const int nb = wsI[WI_BATCH + t];
    const int m0 = blockIdx.y * 64;
    if (m0 >= nb) return;
    const int j0 = blockIdx.x * 64;
    __shared__ __align__(16) float As[16][68];
    __shared__ __align__(16) float Ws[16][68];
    const int tid = threadIdx.x;
    const int tx = tid & 15, ty = tid >> 4;
    const int mr = tid >> 2, kq = tid & 3;
    const bool wok = (j0 + mr) < NTOK;
    const float* aRow = h + (size_t)(m0 + mr) * HID + kq * 4;
    const float* wRow = Wfc + (size_t)(wok ? (j0 + mr) : 0) * HID + kq * 4;

    float acc[4][4] = {};
    for (int kc = 0; kc < HID; kc += 16) {
        float4 a4 = *(const float4*)(aRow + kc);
        float4 w4 = *(const float4*)(wRow + kc);
        As[kq * 4 + 0][mr] = a4.x; As[kq * 4 + 1][mr] = a4.y;
        As[kq * 4 + 2][mr] = a4.z; As[kq * 4 + 3][mr] = a4.w;
        Ws[kq * 4 + 0][mr] = w4.x; Ws[kq * 4 + 1][mr] = w4.y;
        Ws[kq * 4 + 2][mr] = w4.z; Ws[kq * 4 + 3][mr] = w4.w;
        __syncthreads();
#pragma unroll
        for (int kk = 0; kk < 16; ++kk) {
            float4 a = *(const float4*)&As[kk][ty * 4];
            float4 w = *(const float4*)&Ws[kk][tx * 4];
            acc[0][0] += a.x * w.x; acc[0][1] += a.x * w.y; acc[0][2] += a.x * w.z; acc[0][3] += a.x * w.w;
            acc[1][0] += a.y * w.x; acc[1][1] += a.y * w.y; acc[1][2] += a.y * w.z; acc[1][3] += a.y * w.w;
            acc[2][0] += a.z * w.x; acc[2][1] += a.z * w.y; acc[2][2] += a.z * w.z; acc[2][3] += a.z * w.w;
            acc[3][0] += a.w * w.x; acc[3][1] += a.w * w.y; acc[3][2] += a.w * w.z; acc[3][3] += a.w * w.w;
        }
        __syncthreads();
    }
    const int offt = wsI[WI_OFF + t];
    const int col = j0 + tx * 4;
    if (col + 3 < NTOK) {
        float4 bv4 = *(const float4*)(bfc + col);
#pragma unroll
        for (int i = 0; i < 4; ++i) {
            int row = m0 + ty * 4 + i;
            if (row < nb) {
                float4 o;
                o.x = acc[i][0] + bv4.x; o.y = acc[i][1] + bv4.y;
                o.z = acc[i][2] + bv4.z; o.w = acc[i][3] + bv4.w;
                *(float4*)&out[(size_t)(offt + row) * NTOK + col] = o;
            }
        }
    } else {
#pragma unroll
        for (int i = 0; i < 4; ++i) {
            int row = m0 + ty * 4 + i;
            if (row < nb) {
#pragma unroll
                for (int jj = 0; jj < 4; ++jj) {
                    int c = col + jj;
                    if (c < NTOK) out[(size_t)(offt + row) * NTOK + c] = acc[i][jj] + bfc[c];
                }
            }
        }
    }
}

// ---------------------------------------------------------------- attention (pq-reduce + scores + softmax + att_v + emb)
__global__ __launch_bounds__(256) void att_kernel(const float* __restrict__ part1,
                                                  const float* __restrict__ bq,
                                                  const float* __restrict__ pvw,
                                                  const float* __restrict__ v,
                                                  const int* __restrict__ caption,
                                                  const float* __restrict__ emb,
                                                  const int* __restrict__ wsI, int t,
                                                  float* __restrict__ xin) {
    const int nb = wsI[WI_BATCH + t];
    const int s = blockIdx.x;
    if (s >= nb) return;
    const int tid = threadIdx.x;
    __shared__ float pqs[HID];
    __shared__ float sc[64];

    // phase 0: reduce pq partials, + bias, relu
    for (int j = tid; j < HID; j += 256) {
        float a = bq[j];
#pragma unroll
        for (int sl = 0; sl < 8; ++sl) a += part1[((size_t)sl * NBATCH + s) * HID + j];
        pqs[j] = fmaxf(a, 0.f);
    }
    __syncthreads();

    // phase 1: 36 attention scores
    const int w = tid >> 6, lane = tid & 63;
    for (int k = w; k < KREG; k += 4) {
        const float* pr = pvw + ((size_t)s * KREG + k) * HID;
        float a = 0.f;
        for (int hh = lane; hh < HID; hh += 64) a += pr[hh] * pqs[hh];
#pragma unroll
        for (int o = 32; o > 0; o >>= 1) a += __shfl_down(a, o);
        if (lane == 0) sc[k] = a;
    }
    __syncthreads();

    // phase 2: softmax over 36 (single wave)
    if (tid < 64) {
        float x = (tid < KREG) ? sc[tid] : -1e30f;
        float m = x;
#pragma unroll
        for (int o = 32; o > 0; o >>= 1) m = fmaxf(m, __shfl_xor(m, o));
        float e = (tid < KREG) ? expf(x - m) : 0.f;
        float sum = e;
#pragma unroll
        for (int o = 32; o > 0; o >>= 1) sum += __shfl_xor(sum, o);
        if (tid < KREG) sc[tid] = e / sum;
    }
    __syncthreads();

    // phase 3: att_v -> xin[s][512 + d]; emb -> xin[s][0..511]
    const float* vrow = v + (size_t)wsI[WI_ORDER + s] * KREG * VD;
    for (int d = tid; d < VD; d += 256) {
        float a = 0.f;
#pragma unroll
        for (int k = 0; k < KREG; ++k) a += sc[k] * vrow[(size_t)k * VD + d];
        xin[(size_t)s * XIN_D + EMB + d] = a;
    }
    const int tok = caption[wsI[WI_ORDER + s] * ML + t];
    const float* er = emb + (size_t)tok * EMB;
    for (int e = tid; e < EMB; e += 256) xin[(size_t)s * XIN_D + e] = er[e];
}

// ---------------------------------------------------------------- GRU update (reduce gi/gh partials + gates)
__global__ __launch_bounds__(256) void gru_kernel(const float* __restrict__ part2,
                                                  const float* __restrict__ part3,
                                                  const float* __restrict__ bih,
                                                  const float* __restrict__ bhh,
                                                  const int* __restrict__ wsI, int t,
                                                  float* __restrict__ h) {
    const int nb = wsI[WI_BATCH + t];
    const int s = blockIdx.x;
    if (s >= nb) return;
    const int j = blockIdx.y * 256 + threadIdx.x;
    float gir = bih[j], giz = bih[j + HID], gin = bih[j + 2 * HID];
    float ghr = bhh[j], ghz = bhh[j + HID], ghn = bhh[j + 2 * HID];
#pragma unroll
    for (int sl = 0; sl < 8; ++sl) {
        const float* p2 = part2 + ((size_t)sl * NBATCH + s) * G3;
        gir += p2[j]; giz += p2[j + HID]; gin += p2[j + 2 * HID];
        const float* p3 = part3 + ((size_t)sl * NBATCH + s) * G3;
        ghr += p3[j]; ghz += p3[j + HID]; ghn += p3[j + 2 * HID];
    }
    float r = sigmoidf_(gir + ghr);
    float z = sigmoidf_(giz + ghz);
    float n = tanhf(gin + r * ghn);
    size_t idx = (size_t)s * HID + j;
    h[idx] = (1.f - z) * n + z * h[idx];
}

// ---------------------------------------------------------------- in-place softmax over time dim
__global__ __launch_bounds__(256) void softmax_time_kernel(const int* __restrict__ wsI,
                                                           float* __restrict__ out) {
    const int n = blockIdx.x * 256 + threadIdx.x;
    if (n >= NTOK) return;
    const int s = blockIdx.y;
    const int dc = wsI[WI_DEC + s];  // 1..19
    float l[NSTEP];
    float m = 0.f;  // the (20-dc) zero slots participate in the max
#pragma unroll
    for (int t = 0; t < NSTEP; ++t) {
        float val = -1e30f;
        if (t < dc) val = out[(size_t)(wsI[WI_OFF + t] + s) * NTOK + n];
        l[t] = val;
        m = fmaxf(m, val);
    }
    float denom = (float)(ML - dc) * expf(-m);
    float e[NSTEP];
#pragma unroll
    for (int t = 0; t < NSTEP; ++t) {
        e[t] = expf(l[t] - m);
        if (t < dc) denom += e[t];
    }
#pragma unroll
    for (int t = 0; t < NSTEP; ++t)
        if (t < dc) out[(size_t)(wsI[WI_OFF + t] + s) * NTOK + n] = e[t] / denom;
}

// ---------------------------------------------------------------- targets (as float)
__global__ __launch_bounds__(128) void target_kernel(const int* __restrict__ caption,
                                                     const int* __restrict__ wsI,
                                                     float* __restrict__ out) {
    const int t = blockIdx.x, s = threadIdx.x;
    if (s < wsI[WI_BATCH + t]) {
        size_t base = (size_t)wsI[WI_P] * NTOK;
        out[base + wsI[WI_OFF + t] + s] = (float)caption[wsI[WI_ORDER + s] * ML + t + 1];
    }
}

// ---------------------------------------------------------------- launch
extern "C" void kernel_launch(void* const* d_in, const int* in_sizes, int n_in,
                              void* d_out, int out_size, void* d_ws, size_t ws_size,
                              hipStream_t stream) {
    const float* v       = (const float*)d_in[0];
    const int*   caption = (const int*)d_in[1];
    const int*   cap_len = (const int*)d_in[2];
    const float* emb     = (const float*)d_in[3];
    const float* Wv      = (const float*)d_in[4];
    const float* bv      = (const float*)d_in[5];
    const float* Wq      = (const float*)d_in[6];
    const float* bq      = (const float*)d_in[7];
    const float* wa      = (const float*)d_in[8];
    // d_in[9] = ba: dropped (softmax shift-invariant)
    const float* Wih     = (const float*)d_in[10];
    const float* Whh     = (const float*)d_in[11];
    const float* bih     = (const float*)d_in[12];
    const float* bhh     = (const float*)d_in[13];
    const float* Wfc     = (const float*)d_in[14];
    const float* bfc     = (const float*)d_in[15];
    float* out = (float*)d_out;

    int* wsI = (int*)d_ws;
    float* wsF = (float*)d_ws + 1024;          // 4 KB int/control area
    float* pvw   = wsF;                        // 4608*1024
    float* xin   = pvw + 4608 * 1024;          // 128*2560
    float* h     = xin + NBATCH * XIN_D;       // 128*1024
    float* part1 = h + NBATCH * HID;           // 8*128*1024
    float* part2 = part1 + 8 * NBATCH * HID;   // 8*128*3072
    float* part3 = part2 + 8 * NBATCH * G3;    // 8*128*3072

    prep_kernel<<<1, 128, 0, stream>>>(cap_len, wsI);
    h_init_kernel<<<(NBATCH * HID) / 256, 256, 0, stream>>>(h);
    pv_gemm_kernel<<<dim3(HID / 64, (NBATCH * KREG) / 64), 256, 0, stream>>>(v, Wv, bv, wa, wsI, pvw);

    for (int t = 0; t < NSTEP; ++t) {
        pq_gemm_kernel<<<dim3(HID / 64, 2, 8), 256, 0, stream>>>(h, Wq, wsI, t, part1);
        att_kernel<<<NBATCH, 256, 0, stream>>>(part1, bq, pvw, v, caption, emb, wsI, t, xin);
        gemm_nt_splitk_kernel<<<dim3(G3 / 64, 2, 8), 256, 0, stream>>>(xin, XIN_D, Wih, wsI, t, G3, XIN_D / 8, part2);
        gemm_nt_splitk_kernel<<<dim3(G3 / 64, 2, 8), 256, 0, stream>>>(h, HID, Whh, wsI, t, G3, HID / 8, part3);
        gru_kernel<<<dim3(NBATCH, HID / 256), 256, 0, stream>>>(part2, part3, bih, bhh, wsI, t, h);
        logits_kernel<<<dim3((NTOK + 63) / 64, 2), 256, 0, stream>>>(h, Wfc, bfc, wsI, t, out);
    }

    softmax_time_kernel<<<dim3((NTOK + 255) / 256, NBATCH), 256, 0, stream>>>(wsI, out);
    target_kernel<<<NSTEP, 128, 0, stream>>>(caption, wsI, out);
    (void)in_sizes; (void)n_in; (void)out_size; (void)ws_size;
}

// Round 2
// 2748.666 us; speedup vs baseline: 1.4727x; 1.4727x over previous
//
#include <hip/hip_runtime.h>
#include <math.h>

#define NTOK 20000
#define NTOKP 20096   // padded to multiple of 128
#define EMB 512
#define HID 1024
#define VD 2048
#define ML 20
#define NBATCH 128
#define KREG 36
#define NSTEP 19
#define XIN_D 2560
#define G3 3072

// int workspace layout (indices into (int*)d_ws)
#define WI_ORDER 0
#define WI_DEC 128
#define WI_BATCH 256
#define WI_OFF 288
#define WI_P 320

typedef short short8v __attribute__((ext_vector_type(8)));
typedef unsigned short ushort8v __attribute__((ext_vector_type(8)));
typedef float f32x4 __attribute__((ext_vector_type(4)));

static __device__ __forceinline__ float sigmoidf_(float x) { return 1.f / (1.f + expf(-x)); }

static __device__ __forceinline__ unsigned short f2bf(float x) {
    unsigned int b = __float_as_uint(x);
    return (unsigned short)((b + 0x7FFFu + ((b >> 16) & 1u)) >> 16);
}
static __device__ __forceinline__ float bf2f(unsigned short h) {
    return __uint_as_float(((unsigned int)h) << 16);
}

// ---------------------------------------------------------------- prep
__global__ __launch_bounds__(128) void prep_kernel(const int* __restrict__ cap_len,
                                                   int* __restrict__ wsI) {
    __shared__ int cl[NBATCH], sord[NBATCH], sdec[NBATCH], sbat[NSTEP];
    int b = threadIdx.x;
    cl[b] = cap_len[b];
    __syncthreads();
    int my = cl[b], rank = 0;
    for (int j = 0; j < NBATCH; ++j) {
        int o = cl[j];
        rank += (o > my) || (o == my && j < b);
    }
    sord[rank] = b;
    sdec[rank] = my - 1;
    __syncthreads();
    wsI[WI_ORDER + b] = sord[b];
    wsI[WI_DEC + b] = sdec[b];
    if (b < NSTEP) {
        int c = 0;
        for (int s = 0; s < NBATCH; ++s) c += (sdec[s] > b);
        sbat[b] = c;
        wsI[WI_BATCH + b] = c;
    }
    __syncthreads();
    if (b == 0) {
        int run = 0;
        for (int t = 0; t < NSTEP; ++t) { wsI[WI_OFF + t] = run; run += sbat[t]; }
        wsI[WI_P] = run;
    }
}

// ---------------------------------------------------------------- h = 0 (f32 + bf16)
__global__ __launch_bounds__(256) void h_init_kernel(float* __restrict__ h,
                                                     unsigned short* __restrict__ hbf) {
    int i = blockIdx.x * 256 + threadIdx.x;
    h[i] = 0.f;
    hbf[i] = 0;
}

// ---------------------------------------------------------------- Wfc -> bf16 (padded rows zeroed)
__global__ __launch_bounds__(256) void cvt_wfc_kernel(const float* __restrict__ W,
                                                      unsigned short* __restrict__ dst) {
    size_t i8 = ((size_t)blockIdx.x * 256 + threadIdx.x) * 8;  // over NTOKP*HID
    int row = (int)(i8 >> 10);
    ushort8v o;
    if (row < NTOK) {
        float4 a = *(const float4*)(W + i8);
        float4 b = *(const float4*)(W + i8 + 4);
        o[0] = f2bf(a.x); o[1] = f2bf(a.y); o[2] = f2bf(a.z); o[3] = f2bf(a.w);
        o[4] = f2bf(b.x); o[5] = f2bf(b.y); o[6] = f2bf(b.z); o[7] = f2bf(b.w);
    } else {
        for (int j = 0; j < 8; ++j) o[j] = 0;
    }
    *(ushort8v*)(dst + i8) = o;
}

// ---------------------------------------------------------------- Wv [2048][1024] -> WvT hi/lo [1024][2048]
__global__ __launch_bounds__(256) void trans_split_wv_kernel(const float* __restrict__ W,
                                                             unsigned short* __restrict__ hi,
                                                             unsigned short* __restrict__ lo) {
    __shared__ float t[32][33];
    const int k0 = blockIdx.x * 32, n0 = blockIdx.y * 32;
    const int tx = threadIdx.x & 31, ty = threadIdx.x >> 5;  // ty in [0,8)
#pragma unroll
    for (int i = 0; i < 4; ++i) {
        int r = ty + i * 8;
        t[r][tx] = W[(size_t)(k0 + r) * HID + n0 + tx];
    }
    __syncthreads();
#pragma unroll
    for (int i = 0; i < 4; ++i) {
        int rn = ty + i * 8;
        float x = t[tx][rn];  // = W[k0+tx][n0+rn]
        unsigned short h = f2bf(x);
        unsigned short l = f2bf(x - bf2f(h));
        hi[(size_t)(n0 + rn) * VD + k0 + tx] = h;
        lo[(size_t)(n0 + rn) * VD + k0 + tx] = l;
    }
}

// ---------------------------------------------------------------- gather v by order + split hi/lo
__global__ __launch_bounds__(256) void gather_split_v_kernel(const float* __restrict__ v,
                                                             const int* __restrict__ wsI,
                                                             unsigned short* __restrict__ hi,
                                                             unsigned short* __restrict__ lo) {
    const int r = blockIdx.x;           // 0..4607 : s*36+k
    const int s = r / KREG, k = r % KREG;
    const float* src = v + ((size_t)wsI[WI_ORDER + s] * KREG + k) * VD + threadIdx.x * 8;
    float4 a = *(const float4*)(src);
    float4 b = *(const float4*)(src + 4);
    ushort8v oh, ol;
    float vals[8] = {a.x, a.y, a.z, a.w, b.x, b.y, b.z, b.w};
#pragma unroll
    for (int j = 0; j < 8; ++j) {
        unsigned short h = f2bf(vals[j]);
        oh[j] = h;
        ol[j] = f2bf(vals[j] - bf2f(h));
    }
    size_t off = (size_t)r * VD + threadIdx.x * 8;
    *(ushort8v*)(hi + off) = oh;
    *(ushort8v*)(lo + off) = ol;
}

// ================================================================ MFMA GEMMs
// Tile: BM=64 x BN=128, BK=64 staged; 4 waves of 32(M)x64(N).
// LDS layout per 64-wide-K tile: element(row,colchunk c16 of 8 bf16) at
// ushort offset row*64 + ((c16 ^ (row&7)) * 8)   (XOR bank swizzle).

// ---- logits: out[off+row][col] = hbf[row] . Wfcbf[col] + bfc[col] (plain bf16, NT)
__global__ __launch_bounds__(256) void logits_mfma_kernel(const unsigned short* __restrict__ hbf,
                                                          const unsigned short* __restrict__ Wbf,
                                                          const float* __restrict__ bfc,
                                                          const int* __restrict__ wsI, int t,
                                                          float* __restrict__ out) {
    const int nb = wsI[WI_BATCH + t];
    const int m0 = blockIdx.y * 64;
    if (m0 >= nb) return;
    const int n0 = blockIdx.x * 128;
    __shared__ unsigned short sA[64 * 64];
    __shared__ unsigned short sB[128 * 64];
    const int tid = threadIdx.x;
    const int w = tid >> 6, l = tid & 63;
    const int wm = (w >> 1) * 32, wn = (w & 1) * 64;
    const int lr = l & 15, lq = l >> 4;
    const int s8 = tid & 7, ar0 = tid >> 3;  // ar0 in [0,32)
    const int slot = (s8 ^ (ar0 & 7)) * 8;

    f32x4 acc[2][4] = {};

    for (int k0 = 0; k0 < HID; k0 += 64) {
        ushort8v ra0 = *(const ushort8v*)(hbf + (size_t)(m0 + ar0) * HID + k0 + s8 * 8);
        ushort8v ra1 = *(const ushort8v*)(hbf + (size_t)(m0 + ar0 + 32) * HID + k0 + s8 * 8);
        ushort8v rb[4];
#pragma unroll
        for (int j = 0; j < 4; ++j)
            rb[j] = *(const ushort8v*)(Wbf + (size_t)(n0 + ar0 + j * 32) * HID + k0 + s8 * 8);
        __syncthreads();
        *(ushort8v*)(sA + ar0 * 64 + slot) = ra0;
        *(ushort8v*)(sA + (ar0 + 32) * 64 + slot) = ra1;
#pragma unroll
        for (int j = 0; j < 4; ++j)
            *(ushort8v*)(sB + (ar0 + j * 32) * 64 + slot) = rb[j];
        __syncthreads();
#pragma unroll
        for (int ks = 0; ks < 2; ++ks) {
            short8v a[2], b[4];
#pragma unroll
            for (int m = 0; m < 2; ++m) {
                int r = wm + m * 16 + lr;
                a[m] = *(const short8v*)(sA + r * 64 + (((ks * 4 + lq) ^ (r & 7)) * 8));
            }
#pragma unroll
            for (int n = 0; n < 4; ++n) {
                int r = wn + n * 16 + lr;
                b[n] = *(const short8v*)(sB + r * 64 + (((ks * 4 + lq) ^ (r & 7)) * 8));
            }
#pragma unroll
            for (int m = 0; m < 2; ++m)
#pragma unroll
                for (int n = 0; n < 4; ++n)
                    acc[m][n] = __builtin_amdgcn_mfma_f32_16x16x32_bf16(a[m], b[n], acc[m][n], 0, 0, 0);
        }
    }

    const int offt = wsI[WI_OFF + t];
#pragma unroll
    for (int m = 0; m < 2; ++m) {
        const int row = m0 + wm + m * 16 + lq * 4;
#pragma unroll
        for (int n = 0; n < 4; ++n) {
            const int col = n0 + wn + n * 16 + lr;
            if (col < NTOK) {
                const float bb = bfc[col];
#pragma unroll
                for (int i = 0; i < 4; ++i) {
                    int r = row + i;
                    if (r < nb) out[(size_t)(offt + r) * NTOK + col] = acc[m][n][i] + bb;
                }
            }
        }
    }
}

// ---- pv (split hi/lo): pvw[row][col] = relu(vrow . WvT[col] + bv[col]) * wa[col]
__global__ __launch_bounds__(256) void pv_mfma_split_kernel(const unsigned short* __restrict__ Ahi,
                                                            const unsigned short* __restrict__ Alo,
                                                            const unsigned short* __restrict__ Bhi,
                                                            const unsigned short* __restrict__ Blo,
                                                            const float* __restrict__ bv,
                                                            const float* __restrict__ wa,
                                                            float* __restrict__ pvw) {
    const int m0 = blockIdx.y * 64;
    const int n0 = blockIdx.x * 128;
    __shared__ unsigned short sAh[64 * 64], sAl[64 * 64];
    __shared__ unsigned short sBh[128 * 64], sBl[128 * 64];
    const int tid = threadIdx.x;
    const int w = tid >> 6, l = tid & 63;
    const int wm = (w >> 1) * 32, wn = (w & 1) * 64;
    const int lr = l & 15, lq = l >> 4;
    const int s8 = tid & 7, ar0 = tid >> 3;
    const int slot = (s8 ^ (ar0 & 7)) * 8;

    f32x4 acc[2][4] = {};

    for (int k0 = 0; k0 < VD; k0 += 64) {
        ushort8v rah[2], ral[2], rbh[4], rbl[4];
#pragma unroll
        for (int j = 0; j < 2; ++j) {
            size_t go = (size_t)(m0 + ar0 + j * 32) * VD + k0 + s8 * 8;
            rah[j] = *(const ushort8v*)(Ahi + go);
            ral[j] = *(const ushort8v*)(Alo + go);
        }
#pragma unroll
        for (int j = 0; j < 4; ++j) {
            size_t go = (size_t)(n0 + ar0 + j * 32) * VD + k0 + s8 * 8;
            rbh[j] = *(const ushort8v*)(Bhi + go);
            rbl[j] = *(const ushort8v*)(Blo + go);
        }
        __syncthreads();
#pragma unroll
        for (int j = 0; j < 2; ++j) {
            *(ushort8v*)(sAh + (ar0 + j * 32) * 64 + slot) = rah[j];
            *(ushort8v*)(sAl + (ar0 + j * 32) * 64 + slot) = ral[j];
        }
#pragma unroll
        for (int j = 0; j < 4; ++j) {
            *(ushort8v*)(sBh + (ar0 + j * 32) * 64 + slot) = rbh[j];
            *(ushort8v*)(sBl + (ar0 + j * 32) * 64 + slot) = rbl[j];
        }
        __syncthreads();
#pragma unroll
        for (int ks = 0; ks < 2; ++ks) {
            short8v ah[2], al[2], bh[4], bl[4];
#pragma unroll
            for (int m = 0; m < 2; ++m) {
                int r = wm + m * 16 + lr;
                int o = r * 64 + (((ks * 4 + lq) ^ (r & 7)) * 8);
                ah[m] = *(const short8v*)(sAh + o);
                al[m] = *(const short8v*)(sAl + o);
            }
#pragma unroll
            for (int n = 0; n < 4; ++n) {
                int r = wn + n * 16 + lr;
                int o = r * 64 + (((ks * 4 + lq) ^ (r & 7)) * 8);
                bh[n] = *(const short8v*)(sBh + o);
                bl[n] = *(const short8v*)(sBl + o);
            }
#pragma unroll
            for (int m = 0; m < 2; ++m)
#pragma unroll
                for (int n = 0; n < 4; ++n) {
                    acc[m][n] = __builtin_amdgcn_mfma_f32_16x16x32_bf16(al[m], bh[n], acc[m][n], 0, 0, 0);
                    acc[m][n] = __builtin_amdgcn_mfma_f32_16x16x32_bf16(ah[m], bl[n], acc[m][n], 0, 0, 0);
                    acc[m][n] = __builtin_amdgcn_mfma_f32_16x16x32_bf16(ah[m], bh[n], acc[m][n], 0, 0, 0);
                }
        }
    }

#pragma unroll
    for (int m = 0; m < 2; ++m) {
        const int row = m0 + wm + m * 16 + lq * 4;
#pragma unroll
        for (int n = 0; n < 4; ++n) {
            const int col = n0 + wn + n * 16 + lr;
            const float bb = bv[col], ww = wa[col];
#pragma unroll
            for (int i = 0; i < 4; ++i)
                pvw[(size_t)(row + i) * HID + col] = fmaxf(acc[m][n][i] + bb, 0.f) * ww;
        }
    }
}

// ---------------------------------------------------------------- pq GEMM (NN, split-K=8) -> partial
__global__ __launch_bounds__(256) void pq_gemm_kernel(const float* __restrict__ h,
                                                      const float* __restrict__ Wq,
                                                      const int* __restrict__ wsI, int t,
                                                      float* __restrict__ part) {
    const int nb = wsI[WI_BATCH + t];
    const int m0 = blockIdx.y * 64;
    if (m0 >= nb) return;
    const int j0 = blockIdx.x * 64;
    const int sl = blockIdx.z;
    const int kbase = sl * 128;
    __shared__ __align__(16) float As[16][68];
    __shared__ __align__(16) float Bs[16][64];
    const int tid = threadIdx.x;
    const int tx = tid & 15, ty = tid >> 4;
    const int mr = tid >> 2, kq = tid & 3;
    const float* aRow = h + (size_t)(m0 + mr) * HID + kq * 4;

    float acc[4][4] = {};
    for (int kc = kbase; kc < kbase + 128; kc += 16) {
        float4 a4 = *(const float4*)(aRow + kc);
        As[kq * 4 + 0][mr] = a4.x; As[kq * 4 + 1][mr] = a4.y;
        As[kq * 4 + 2][mr] = a4.z; As[kq * 4 + 3][mr] = a4.w;
        float4 b4 = *(const float4*)(Wq + (size_t)(kc + (tid >> 4)) * HID + j0 + (tid & 15) * 4);
        *(float4*)&Bs[tid >> 4][(tid & 15) * 4] = b4;
        __syncthreads();
#pragma unroll
        for (int kk = 0; kk < 16; ++kk) {
            float4 a = *(const float4*)&As[kk][ty * 4];
            float4 w = *(const float4*)&Bs[kk][tx * 4];
            acc[0][0] += a.x * w.x; acc[0][1] += a.x * w.y; acc[0][2] += a.x * w.z; acc[0][3] += a.x * w.w;
            acc[1][0] += a.y * w.x; acc[1][1] += a.y * w.y; acc[1][2] += a.y * w.z; acc[1][3] += a.y * w.w;
            acc[2][0] += a.z * w.x; acc[2][1] += a.z * w.y; acc[2][2] += a.z * w.z; acc[2][3] += a.z * w.w;
            acc[3][0] += a.w * w.x; acc[3][1] += a.w * w.y; acc[3][2] += a.w * w.z; acc[3][3] += a.w * w.w;
        }
        __syncthreads();
    }
#pragma unroll
    for (int i = 0; i < 4; ++i) {
        int row = m0 + ty * 4 + i;
        float4 o; o.x = acc[i][0]; o.y = acc[i][1]; o.z = acc[i][2]; o.w = acc[i][3];
        *(float4*)&part[((size_t)sl * NBATCH + row) * HID + j0 + tx * 4] = o;
    }
}

// ---------------------------------------------------------------- generic NT split-K GEMM (gi, gh)
__global__ __launch_bounds__(256) void gemm_nt_splitk_kernel(const float* __restrict__ A, int lda,
                                                             const float* __restrict__ W,
                                                             const int* __restrict__ wsI, int t,
                                                             int N, int Kper,
                                                             float* __restrict__ part) {
    const int nb = wsI[WI_BATCH + t];
    const int m0 = blockIdx.y * 64;
    if (m0 >= nb) return;
    const int j0 = blockIdx.x * 64;
    const int sl = blockIdx.z;
    const int kbase = sl * Kper;
    __shared__ __align__(16) float As[16][68];
    __shared__ __align__(16) float Ws[16][68];
    const int tid = threadIdx.x;
    const int tx = tid & 15, ty = tid >> 4;
    const int mr = tid >> 2, kq = tid & 3;
    const float* aRow = A + (size_t)(m0 + mr) * lda + kq * 4;
    const float* wRow = W + (size_t)(j0 + mr) * lda + kq * 4;

    float acc[4][4] = {};
    for (int kc = kbase; kc < kbase + Kper; kc += 16) {
        float4 a4 = *(const float4*)(aRow + kc);
        float4 w4 = *(const float4*)(wRow + kc);
        As[kq * 4 + 0][mr] = a4.x; As[kq * 4 + 1][mr] = a4.y;
        As[kq * 4 + 2][mr] = a4.z; As[kq * 4 + 3][mr] = a4.w;
        Ws[kq * 4 + 0][mr] = w4.x; Ws[kq * 4 + 1][mr] = w4.y;
        Ws[kq * 4 + 2][mr] = w4.z; Ws[kq * 4 + 3][mr] = w4.w;
        __syncthreads();
#pragma unroll
        for (int kk = 0; kk < 16; ++kk) {
            float4 a = *(const float4*)&As[kk][ty * 4];
            float4 w = *(const float4*)&Ws[kk][tx * 4];
            acc[0][0] += a.x * w.x; acc[0][1] += a.x * w.y; acc[0][2] += a.x * w.z; acc[0][3] += a.x * w.w;
            acc[1][0] += a.y * w.x; acc[1][1] += a.y * w.y; acc[1][2] += a.y * w.z; acc[1][3] += a.y * w.w;
            acc[2][0] += a.z * w.x; acc[2][1] += a.z * w.y; acc[2][2] += a.z * w.z; acc[2][3] += a.z * w.w;
            acc[3][0] += a.w * w.x; acc[3][1] += a.w * w.y; acc[3][2] += a.w * w.z; acc[3][3] += a.w * w.w;
        }
        __syncthreads();
    }
#pragma unroll
    for (int i = 0; i < 4; ++i) {
        int row = m0 + ty * 4 + i;
        float4 o; o.x = acc[i][0]; o.y = acc[i][1]; o.z = acc[i][2]; o.w = acc[i][3];
        *(float4*)&part[((size_t)sl * NBATCH + row) * N + j0 + tx * 4] = o;
    }
}

// ---------------------------------------------------------------- attention
__global__ __launch_bounds__(256) void att_kernel(const float* __restrict__ part1,
                                                  const float* __restrict__ bq,
                                                  const float* __restrict__ pvw,
                                                  const float* __restrict__ v,
                                                  const int* __restrict__ caption,
                                                  const float* __restrict__ emb,
                                                  const int* __restrict__ wsI, int t,
                                                  float* __restrict__ xin) {
    const int nb = wsI[WI_BATCH + t];
    const int s = blockIdx.x;
    if (s >= nb) return;
    const int tid = threadIdx.x;
    __shared__ float pqs[HID];
    __shared__ float sc[64];

    for (int j = tid; j < HID; j += 256) {
        float a = bq[j];
#pragma unroll
        for (int sl = 0; sl < 8; ++sl) a += part1[((size_t)sl * NBATCH + s) * HID + j];
        pqs[j] = fmaxf(a, 0.f);
    }
    __syncthreads();

    const int w = tid >> 6, lane = tid & 63;
    for (int k = w; k < KREG; k += 4) {
        const float* pr = pvw + ((size_t)s * KREG + k) * HID;
        float a = 0.f;
        for (int hh = lane; hh < HID; hh += 64) a += pr[hh] * pqs[hh];
#pragma unroll
        for (int o = 32; o > 0; o >>= 1) a += __shfl_down(a, o);
        if (lane == 0) sc[k] = a;
    }
    __syncthreads();

    if (tid < 64) {
        float x = (tid < KREG) ? sc[tid] : -1e30f;
        float m = x;
#pragma unroll
        for (int o = 32; o > 0; o >>= 1) m = fmaxf(m, __shfl_xor(m, o));
        float e = (tid < KREG) ? expf(x - m) : 0.f;
        float sum = e;
#pragma unroll
        for (int o = 32; o > 0; o >>= 1) sum += __shfl_xor(sum, o);
        if (tid < KREG) sc[tid] = e / sum;
    }
    __syncthreads();

    const float* vrow = v + (size_t)wsI[WI_ORDER + s] * KREG * VD;
    for (int d = tid; d < VD; d += 256) {
        float a = 0.f;
#pragma unroll
        for (int k = 0; k < KREG; ++k) a += sc[k] * vrow[(size_t)k * VD + d];
        xin[(size_t)s * XIN_D + EMB + d] = a;
    }
    const int tok = caption[wsI[WI_ORDER + s] * ML + t];
    const float* er = emb + (size_t)tok * EMB;
    for (int e = tid; e < EMB; e += 256) xin[(size_t)s * XIN_D + e] = er[e];
}

// ---------------------------------------------------------------- GRU update (+ bf16 h mirror)
__global__ __launch_bounds__(256) void gru_kernel(const float* __restrict__ part2,
                                                  const float* __restrict__ part3,
                                                  const float* __restrict__ bih,
                                                  const float* __restrict__ bhh,
                                                  const int* __restrict__ wsI, int t,
                                                  float* __restrict__ h,
                                                  unsigned short* __restrict__ hbf) {
    const int nb = wsI[WI_BATCH + t];
    const int s = blockIdx.x;
    if (s >= nb) return;
    const int j = blockIdx.y * 256 + threadIdx.x;
    float gir = bih[j], giz = bih[j + HID], gin = bih[j + 2 * HID];
    float ghr = bhh[j], ghz = bhh[j + HID], ghn = bhh[j + 2 * HID];
#pragma unroll
    for (int sl = 0; sl < 8; ++sl) {
        const float* p2 = part2 + ((size_t)sl * NBATCH + s) * G3;
        gir += p2[j]; giz += p2[j + HID]; gin += p2[j + 2 * HID];
        const float* p3 = part3 + ((size_t)sl * NBATCH + s) * G3;
        ghr += p3[j]; ghz += p3[j + HID]; ghn += p3[j + 2 * HID];
    }
    float r = sigmoidf_(gir + ghr);
    float z = sigmoidf_(giz + ghz);
    float n = tanhf(gin + r * ghn);
    size_t idx = (size_t)s * HID + j;
    float hn = (1.f - z) * n + z * h[idx];
    h[idx] = hn;
    hbf[idx] = f2bf(hn);
}

// ---------------------------------------------------------------- in-place softmax over time dim
__global__ __launch_bounds__(256) void softmax_time_kernel(const int* __restrict__ wsI,
                                                           float* __restrict__ out) {
    const int n = blockIdx.x * 256 + threadIdx.x;
    if (n >= NTOK) return;
    const int s = blockIdx.y;
    const int dc = wsI[WI_DEC + s];
    float l[NSTEP];
    float m = 0.f;
#pragma unroll
    for (int t = 0; t < NSTEP; ++t) {
        float val = -1e30f;
        if (t < dc) val = out[(size_t)(wsI[WI_OFF + t] + s) * NTOK + n];
        l[t] = val;
        m = fmaxf(m, val);
    }
    float denom = (float)(ML - dc) * expf(-m);
    float e[NSTEP];
#pragma unroll
    for (int t = 0; t < NSTEP; ++t) {
        e[t] = expf(l[t] - m);
        if (t < dc) denom += e[t];
    }
#pragma unroll
    for (int t = 0; t < NSTEP; ++t)
        if (t < dc) out[(size_t)(wsI[WI_OFF + t] + s) * NTOK + n] = e[t] / denom;
}

// ---------------------------------------------------------------- targets
__global__ __launch_bounds__(128) void target_kernel(const int* __restrict__ caption,
                                                     const int* __restrict__ wsI,
                                                     float* __restrict__ out) {
    const int t = blockIdx.x, s = threadIdx.x;
    if (s < wsI[WI_BATCH + t]) {
        size_t base = (size_t)wsI[WI_P] * NTOK;
        out[base + wsI[WI_OFF + t] + s] = (float)caption[wsI[WI_ORDER + s] * ML + t + 1];
    }
}

// ---------------------------------------------------------------- launch
extern "C" void kernel_launch(void* const* d_in, const int* in_sizes, int n_in,
                              void* d_out, int out_size, void* d_ws, size_t ws_size,
                              hipStream_t stream) {
    const float* v       = (const float*)d_in[0];
    const int*   caption = (const int*)d_in[1];
    const int*   cap_len = (const int*)d_in[2];
    const float* emb     = (const float*)d_in[3];
    const float* Wv      = (const float*)d_in[4];
    const float* bv      = (const float*)d_in[5];
    const float* Wq      = (const float*)d_in[6];
    const float* bq      = (const float*)d_in[7];
    const float* wa      = (const float*)d_in[8];
    // d_in[9] = ba: dropped (softmax shift-invariant)
    const float* Wih     = (const float*)d_in[10];
    const float* Whh     = (const float*)d_in[11];
    const float* bih     = (const float*)d_in[12];
    const float* bhh     = (const float*)d_in[13];
    const float* Wfc     = (const float*)d_in[14];
    const float* bfc     = (const float*)d_in[15];
    float* out = (float*)d_out;

    int* wsI = (int*)d_ws;
    float* base  = (float*)d_ws + 1024;
    float* pvw   = base;                        // 4,718,592 f
    float* xin   = pvw + 4718592;               // 327,680 f
    float* h     = xin + NBATCH * XIN_D;        // 131,072 f
    float* U     = h + NBATCH * HID;            // union: 11,534,336 f
    // loop-phase view of U:
    float* part1 = U;                           // 8*128*1024
    float* part2 = part1 + 8 * NBATCH * HID;    // 8*128*3072
    float* part3 = part2 + 8 * NBATCH * G3;     // 8*128*3072
    // pre-phase view of U (disjoint lifetime):
    unsigned short* vhi   = (unsigned short*)U;           // 9,437,184 us
    unsigned short* vlo   = vhi + 9437184;                // 9,437,184 us
    unsigned short* wvthi = vlo + 9437184;                // 2,097,152 us
    unsigned short* wvtlo = wvthi + 2097152;              // 2,097,152 us
    float* tail = U + 11534336;
    unsigned short* hbf   = (unsigned short*)tail;        // 131,072 us
    unsigned short* Wfcbf = hbf + NBATCH * HID;           // 20,578,304 us

    prep_kernel<<<1, 128, 0, stream>>>(cap_len, wsI);
    h_init_kernel<<<(NBATCH * HID) / 256, 256, 0, stream>>>(h, hbf);
    cvt_wfc_kernel<<<(NTOKP * HID / 8) / 256, 256, 0, stream>>>(Wfc, Wfcbf);
    trans_split_wv_kernel<<<dim3(VD / 32, HID / 32), 256, 0, stream>>>(Wv, wvthi, wvtlo);
    gather_split_v_kernel<<<NBATCH * KREG, 256, 0, stream>>>(v, wsI, vhi, vlo);
    pv_mfma_split_kernel<<<dim3(HID / 128, (NBATCH * KREG) / 64), 256, 0, stream>>>(
        vhi, vlo, wvthi, wvtlo, bv, wa, pvw);

    for (int t = 0; t < NSTEP; ++t) {
        pq_gemm_kernel<<<dim3(HID / 64, 2, 8), 256, 0, stream>>>(h, Wq, wsI, t, part1);
        att_kernel<<<NBATCH, 256, 0, stream>>>(part1, bq, pvw, v, caption, emb, wsI, t, xin);
        gemm_nt_splitk_kernel<<<dim3(G3 / 64, 2, 8), 256, 0, stream>>>(xin, XIN_D, Wih, wsI, t, G3, XIN_D / 8, part2);
        gemm_nt_splitk_kernel<<<dim3(G3 / 64, 2, 8), 256, 0, stream>>>(h, HID, Whh, wsI, t, G3, HID / 8, part3);
        gru_kernel<<<dim3(NBATCH, HID / 256), 256, 0, stream>>>(part2, part3, bih, bhh, wsI, t, h, hbf);
        logits_mfma_kernel<<<dim3(NTOKP / 128, 2), 256, 0, stream>>>(hbf, Wfcbf, bfc, wsI, t, out);
    }

    softmax_time_kernel<<<dim3((NTOK + 255) / 256, NBATCH), 256, 0, stream>>>(wsI, out);
    target_kernel<<<NSTEP, 128, 0, stream>>>(caption, wsI, out);
    (void)in_sizes; (void)n_in; (void)out_size; (void)ws_size;
}